// Round 7
// baseline (20.569 us; speedup 1.0000x reference)
//
#include <hip/hip_runtime.h>

constexpr int Q    = 20;
constexpr int EMB  = 64;
constexpr int Bsz  = 16, H = 48, W = 48;
constexpr int HW   = H * W;          // 2304
constexpr int NPIX = Bsz * HW;       // 36864
constexpr int BLOCK = 256;
constexpr int TPP   = 4;             // threads per pixel
constexpr int PIXPB = BLOCK / TPP;   // 64 pixels per block
constexpr int NBLK  = NPIX / PIXPB;  // 576 blocks

// No LDS, no barrier: epilogue reads the original tables from global
// (4.6 KB total -> L1-resident). out[e] = LRelu(scalar
//   + sum_j dT[j]*T[j][e] + sum_j dD[j]*D[j][e] + sum_j dR[j]*R[j][e]
//   + dP0*P[0][e] + dP1*P[1][e]) * ind
__global__ __launch_bounds__(BLOCK)
void act_pre_kernel(const int* __restrict__ unit,
                    const int* __restrict__ atp,  const int* __restrict__ dirp,
                    const int* __restrict__ resp, const int* __restrict__ repp,
                    const float* __restrict__ amtp, const float* __restrict__ np_,
                    const float* __restrict__ Ttab, const float* __restrict__ Dtab,
                    const float* __restrict__ Rtab, const float* __restrict__ Ptab,
                    const float* __restrict__ w1p,  const float* __restrict__ b1p,
                    const float* __restrict__ w2p,  const float* __restrict__ b2p,
                    float* __restrict__ out)
{
    const int tid = threadIdx.x;
    const int pIB = tid >> 2;          // 0..63
    const int t   = tid & 3;           // 0..3
    const int pix = blockIdx.x * PIXPB + pIB;

    // ---- per-pixel global loads (thread t owns q in [4t,4t+4) and q=16+t) ----
    const int base = pix * Q + t * 4;
    const int tail = pix * Q + 16 + t;
    const int4   av = *reinterpret_cast<const int4*>(atp  + base);
    const int4   dv = *reinterpret_cast<const int4*>(dirp + base);
    const int4   rv = *reinterpret_cast<const int4*>(resp + base);
    const int4   pv = *reinterpret_cast<const int4*>(repp + base);
    const float4 mv = *reinterpret_cast<const float4*>(amtp + base);
    const float4 nv = *reinterpret_cast<const float4*>(np_  + base);
    const int   as = atp[tail],  ds2 = dirp[tail], rs = resp[tail], ps = repp[tail];
    const float ms = amtp[tail], ns = np_[tail];
    const int   uu = unit[pix];
    const float4 wv = *reinterpret_cast<const float4*>(w1p + t * 4);
    const float  ws = w1p[16 + t];

    // uniform scalars
    const float w20 = w2p[0], w21 = w2p[1], w22 = w2p[2];
    const float w23 = w2p[3], w24 = w2p[4], w25 = w2p[5];
    const float constC = b1p[0] * (w20 + w21 + w22 + w23 + w24 + w25) + b2p[0];

    // ---- coefficient accumulation (register-only, static indexing) ----
    const int   ai[5] = {av.x, av.y, av.z, av.w, as};
    const int   di[5] = {dv.x, dv.y, dv.z, dv.w, ds2};
    const int   ri[5] = {rv.x, rv.y, rv.z, rv.w, rs};
    const int   pi[5] = {pv.x, pv.y, pv.z, pv.w, ps};
    const float mf[5] = {mv.x, mv.y, mv.z, mv.w, ms};
    const float nf[5] = {nv.x, nv.y, nv.z, nv.w, ns};
    const float wf[5] = {wv.x, wv.y, wv.z, wv.w, ws};

    float cT[6] = {}, cD[5] = {}, cR[5] = {};
    float rep = 0.f, amtAcc = 0.f, nAcc = 0.f;
    float sumw = wf[0] + wf[1] + wf[2] + wf[3] + wf[4];
    #pragma unroll
    for (int j = 0; j < 5; ++j) {
        const float wq = wf[j];
        #pragma unroll
        for (int k = 0; k < 6; ++k) cT[k] += (ai[j] == k) ? wq : 0.f;
        #pragma unroll
        for (int k = 0; k < 5; ++k) cD[k] += (di[j] == k) ? wq : 0.f;
        #pragma unroll
        for (int k = 0; k < 5; ++k) cR[k] += (ri[j] == k) ? wq : 0.f;
        rep    += (pi[j] != 0) ? wq : 0.f;
        amtAcc += wq * mf[j];
        nAcc   += wq * nf[j];
    }

    // ---- butterfly allreduce over the 4 threads of this pixel (19 values) ----
    #define RED4(x) { x += __shfl_xor(x, 1); x += __shfl_xor(x, 2); }
    #pragma unroll
    for (int k = 0; k < 6; ++k) RED4(cT[k]);
    #pragma unroll
    for (int k = 0; k < 5; ++k) RED4(cD[k]);
    #pragma unroll
    for (int k = 0; k < 5; ++k) RED4(cR[k]);
    RED4(rep); RED4(amtAcc); RED4(nAcc); RED4(sumw);
    #undef RED4

    const float scalar = w23 * amtAcc + w25 * nAcc + constC;
    const float ind = (uu != 0) ? 1.f : 0.f;

    // scaled coefficients over the ORIGINAL table rows
    float dT[6], dD[5], dR[5];
    #pragma unroll
    for (int k = 0; k < 6; ++k) dT[k] = w20 * cT[k];
    #pragma unroll
    for (int k = 0; k < 5; ++k) dD[k] = w21 * cD[k];
    #pragma unroll
    for (int k = 0; k < 5; ++k) dR[k] = w22 * cR[k];
    const float dP0 = w24 * (sumw - rep);
    const float dP1 = w24 * rep;

    const int b  = pix / HW;
    const int hw = pix - b * HW;
    float* outp = out + b * (EMB * HW) + hw;

    // ---- epilogue: each thread computes channels [16t, 16t+16) directly
    //      from the global tables (L1-hot, 4.6 KB total). No barrier. ----
    #pragma unroll
    for (int i = 0; i < 4; ++i) {
        const int e0 = t * 16 + i * 4;
        float a0 = scalar, a1 = scalar, a2 = scalar, a3 = scalar;
        #pragma unroll
        for (int j = 0; j < 6; ++j) {
            const float4 sv = *reinterpret_cast<const float4*>(Ttab + j * EMB + e0);
            a0 += dT[j] * sv.x;  a1 += dT[j] * sv.y;
            a2 += dT[j] * sv.z;  a3 += dT[j] * sv.w;
        }
        #pragma unroll
        for (int j = 0; j < 5; ++j) {
            const float4 sv = *reinterpret_cast<const float4*>(Dtab + j * EMB + e0);
            a0 += dD[j] * sv.x;  a1 += dD[j] * sv.y;
            a2 += dD[j] * sv.z;  a3 += dD[j] * sv.w;
        }
        #pragma unroll
        for (int j = 0; j < 5; ++j) {
            const float4 sv = *reinterpret_cast<const float4*>(Rtab + j * EMB + e0);
            a0 += dR[j] * sv.x;  a1 += dR[j] * sv.y;
            a2 += dR[j] * sv.z;  a3 += dR[j] * sv.w;
        }
        {
            const float4 p0 = *reinterpret_cast<const float4*>(Ptab + e0);
            const float4 p1 = *reinterpret_cast<const float4*>(Ptab + EMB + e0);
            a0 += dP0 * p0.x + dP1 * p1.x;
            a1 += dP0 * p0.y + dP1 * p1.y;
            a2 += dP0 * p0.z + dP1 * p1.z;
            a3 += dP0 * p0.w + dP1 * p1.w;
        }
        a0 = ((a0 >= 0.f) ? a0 : 0.01f * a0) * ind;
        a1 = ((a1 >= 0.f) ? a1 : 0.01f * a1) * ind;
        a2 = ((a2 >= 0.f) ? a2 : 0.01f * a2) * ind;
        a3 = ((a3 >= 0.f) ? a3 : 0.01f * a3) * ind;
        outp[(e0 + 0) * HW] = a0;
        outp[(e0 + 1) * HW] = a1;
        outp[(e0 + 2) * HW] = a2;
        outp[(e0 + 3) * HW] = a3;
    }
}

extern "C" void kernel_launch(void* const* d_in, const int* in_sizes, int n_in,
                              void* d_out, int out_size, void* d_ws, size_t ws_size,
                              hipStream_t stream) {
    const int*   unit = (const int*)  d_in[0];
    const int*   atp  = (const int*)  d_in[1];
    const int*   dirp = (const int*)  d_in[2];
    const int*   resp = (const int*)  d_in[3];
    const int*   repp = (const int*)  d_in[4];
    const float* amtp = (const float*)d_in[5];
    const float* np_  = (const float*)d_in[6];
    const float* Ttab = (const float*)d_in[7];
    const float* Dtab = (const float*)d_in[8];
    const float* Rtab = (const float*)d_in[9];
    const float* Ptab = (const float*)d_in[10];
    const float* w1p  = (const float*)d_in[11];
    const float* b1p  = (const float*)d_in[12];
    const float* w2p  = (const float*)d_in[13];
    const float* b2p  = (const float*)d_in[14];
    float* out = (float*)d_out;

    act_pre_kernel<<<NBLK, BLOCK, 0, stream>>>(
        unit, atp, dirp, resp, repp, amtp, np_,
        Ttab, Dtab, Rtab, Ptab, w1p, b1p, w2p, b2p, out);
}

// Round 8
// 16.896 us; speedup vs baseline: 1.2174x; 1.2174x over previous
//
#include <hip/hip_runtime.h>

constexpr int Q    = 20;
constexpr int EMB  = 64;
constexpr int Bsz  = 16, H = 48, W = 48;
constexpr int HW   = H * W;          // 2304
constexpr int NPIX = Bsz * HW;       // 36864
constexpr int BLOCK = 64;            // one wave per block
constexpr int NBLK  = NPIX / BLOCK;  // 576 blocks

// One thread = one pixel. No shuffles, no cross-wave deps.
// LDS table rows: 0-4: w20*(T[k]-T[5]); 5-8: w21*(D[k]-D[4]);
// 9-12: w22*(R[k]-R[4]); 13: w24*(P[1]-P[0]);
// 14: sumw1*(w20*T5 + w21*D4 + w22*R4 + w24*P0)
__global__ __launch_bounds__(BLOCK, 3)
void act_pre_kernel(const int* __restrict__ unit,
                    const int* __restrict__ atp,  const int* __restrict__ dirp,
                    const int* __restrict__ resp, const int* __restrict__ repp,
                    const float* __restrict__ amtp, const float* __restrict__ np_,
                    const float* __restrict__ Ttab, const float* __restrict__ Dtab,
                    const float* __restrict__ Rtab, const float* __restrict__ Ptab,
                    const float* __restrict__ w1p,  const float* __restrict__ b1p,
                    const float* __restrict__ w2p,  const float* __restrict__ b2p,
                    float* __restrict__ out)
{
    __shared__ float sc[15][EMB];

    const int tid = threadIdx.x;     // 0..63 : lane = pixel-in-block = e-index for fill
    const int pix = blockIdx.x * BLOCK + tid;

    // ---- per-pixel loads: exactly 5 aligned int4/float4 per array (80B), no tails ----
    const int base = pix * Q;
    int4   av[5], dv[5], rv[5], pv[5];
    float4 mv[5], nv[5];
    #pragma unroll
    for (int v = 0; v < 5; ++v) {
        av[v] = reinterpret_cast<const int4*>(atp  + base)[v];
        dv[v] = reinterpret_cast<const int4*>(dirp + base)[v];
        rv[v] = reinterpret_cast<const int4*>(resp + base)[v];
        pv[v] = reinterpret_cast<const int4*>(repp + base)[v];
        mv[v] = reinterpret_cast<const float4*>(amtp + base)[v];
        nv[v] = reinterpret_cast<const float4*>(np_  + base)[v];
    }
    const int uu = unit[pix];

    // ---- wave-uniform parameters -> SGPRs ----
    float w1v[Q];
    #pragma unroll
    for (int q = 0; q < Q; ++q) w1v[q] = w1p[q];
    float sumw = 0.f;
    #pragma unroll
    for (int q = 0; q < Q; ++q) sumw += w1v[q];
    const float w20 = w2p[0], w21 = w2p[1], w22 = w2p[2];
    const float w23 = w2p[3], w24 = w2p[4], w25 = w2p[5];
    const float constC = b1p[0] * (w20 + w21 + w22 + w23 + w24 + w25) + b2p[0];

    // ---- LDS table fill: thread tid fills element tid of each row ----
    const float t5 = Ttab[5 * EMB + tid];
    const float d4 = Dtab[4 * EMB + tid];
    const float r4 = Rtab[4 * EMB + tid];
    const float p0 = Ptab[tid];
    const float p1 = Ptab[EMB + tid];
    #pragma unroll
    for (int k = 0; k < 5; ++k) sc[k][tid]     = w20 * (Ttab[k * EMB + tid] - t5);
    #pragma unroll
    for (int k = 0; k < 4; ++k) sc[5 + k][tid] = w21 * (Dtab[k * EMB + tid] - d4);
    #pragma unroll
    for (int k = 0; k < 4; ++k) sc[9 + k][tid] = w22 * (Rtab[k * EMB + tid] - r4);
    sc[13][tid] = w24 * (p1 - p0);
    sc[14][tid] = sumw * (w20 * t5 + w21 * d4 + w22 * r4 + w24 * p0);

    // ---- bucket accumulation: whole pixel in one thread, zero shuffles ----
    float cT0 = 0.f, cT1 = 0.f, cT2 = 0.f, cT3 = 0.f, cT4 = 0.f;
    float cD0 = 0.f, cD1 = 0.f, cD2 = 0.f, cD3 = 0.f;
    float cR0 = 0.f, cR1 = 0.f, cR2 = 0.f, cR3 = 0.f;
    float rep = 0.f, amtAcc = 0.f, nAcc = 0.f;

    auto procq = [&](int a, int d, int r, int p, float m, float n, float wq) {
        cT0 += (a == 0) ? wq : 0.f;  cT1 += (a == 1) ? wq : 0.f;
        cT2 += (a == 2) ? wq : 0.f;  cT3 += (a == 3) ? wq : 0.f;
        cT4 += (a == 4) ? wq : 0.f;
        cD0 += (d == 0) ? wq : 0.f;  cD1 += (d == 1) ? wq : 0.f;
        cD2 += (d == 2) ? wq : 0.f;  cD3 += (d == 3) ? wq : 0.f;
        cR0 += (r == 0) ? wq : 0.f;  cR1 += (r == 1) ? wq : 0.f;
        cR2 += (r == 2) ? wq : 0.f;  cR3 += (r == 3) ? wq : 0.f;
        rep    += (p != 0) ? wq : 0.f;
        amtAcc += wq * m;
        nAcc   += wq * n;
    };
    #pragma unroll
    for (int v = 0; v < 5; ++v) {
        procq(av[v].x, dv[v].x, rv[v].x, pv[v].x, mv[v].x, nv[v].x, w1v[4 * v + 0]);
        procq(av[v].y, dv[v].y, rv[v].y, pv[v].y, mv[v].y, nv[v].y, w1v[4 * v + 1]);
        procq(av[v].z, dv[v].z, rv[v].z, pv[v].z, mv[v].z, nv[v].z, w1v[4 * v + 2]);
        procq(av[v].w, dv[v].w, rv[v].w, pv[v].w, mv[v].w, nv[v].w, w1v[4 * v + 3]);
    }

    const float scalar = w23 * amtAcc + w25 * nAcc + constC;
    const float ind = (uu != 0) ? 1.f : 0.f;

    float cf[14];
    cf[0] = cT0; cf[1] = cT1; cf[2] = cT2; cf[3] = cT3; cf[4] = cT4;
    cf[5] = cD0; cf[6] = cD1; cf[7] = cD2; cf[8] = cD3;
    cf[9] = cR0; cf[10] = cR1; cf[11] = cR2; cf[12] = cR3;
    cf[13] = rep;

    const int b  = pix / HW;
    const int hw = pix - b * HW;
    float* outp = out + b * (EMB * HW) + hw;

    __syncthreads();   // single wave: effectively just a waitcnt

    // ---- compact epilogue loop: 16 iterations, LDS reads broadcast (uniform addr) ----
    for (int e0 = 0; e0 < EMB; e0 += 4) {
        const float4 bv = *reinterpret_cast<const float4*>(&sc[14][e0]);
        float a0 = scalar + bv.x, a1 = scalar + bv.y;
        float a2 = scalar + bv.z, a3 = scalar + bv.w;
        #pragma unroll
        for (int k = 0; k < 14; ++k) {
            const float4 sv = *reinterpret_cast<const float4*>(&sc[k][e0]);
            a0 += cf[k] * sv.x;
            a1 += cf[k] * sv.y;
            a2 += cf[k] * sv.z;
            a3 += cf[k] * sv.w;
        }
        a0 = ((a0 >= 0.f) ? a0 : 0.01f * a0) * ind;
        a1 = ((a1 >= 0.f) ? a1 : 0.01f * a1) * ind;
        a2 = ((a2 >= 0.f) ? a2 : 0.01f * a2) * ind;
        a3 = ((a3 >= 0.f) ? a3 : 0.01f * a3) * ind;
        outp[(e0 + 0) * HW] = a0;
        outp[(e0 + 1) * HW] = a1;
        outp[(e0 + 2) * HW] = a2;
        outp[(e0 + 3) * HW] = a3;
    }
}

extern "C" void kernel_launch(void* const* d_in, const int* in_sizes, int n_in,
                              void* d_out, int out_size, void* d_ws, size_t ws_size,
                              hipStream_t stream) {
    const int*   unit = (const int*)  d_in[0];
    const int*   atp  = (const int*)  d_in[1];
    const int*   dirp = (const int*)  d_in[2];
    const int*   resp = (const int*)  d_in[3];
    const int*   repp = (const int*)  d_in[4];
    const float* amtp = (const float*)d_in[5];
    const float* np_  = (const float*)d_in[6];
    const float* Ttab = (const float*)d_in[7];
    const float* Dtab = (const float*)d_in[8];
    const float* Rtab = (const float*)d_in[9];
    const float* Ptab = (const float*)d_in[10];
    const float* w1p  = (const float*)d_in[11];
    const float* b1p  = (const float*)d_in[12];
    const float* w2p  = (const float*)d_in[13];
    const float* b2p  = (const float*)d_in[14];
    float* out = (float*)d_out;

    act_pre_kernel<<<NBLK, BLOCK, 0, stream>>>(
        unit, atp, dirp, resp, repp, amtp, np_,
        Ttab, Dtab, Rtab, Ptab, w1p, b1p, w2p, b2p, out);
}